// Round 4
// baseline (1091.972 us; speedup 1.0000x reference)
//
#include <hip/hip_runtime.h>
#include <math.h>

// Problem constants (from reference)
#define S_TOK 8192
#define E_DIM 2048
#define NHEAD 8
#define HDIM  256
#define NGRP  256
#define GN    1024   // NGRP*4  (flattened noun rows; attrs same count)
#define MROWS 2048   // 2*GN    (e-path rows ++ h-path rows)
#define NKV   4096   // K and V projections side by side
#define KD    2048

#define MAXNORM 0.99999f
#define MINNORM 1e-15f
#define ALPHA_C 1.1f
#define BETA_C  1.2f

typedef __attribute__((ext_vector_type(8))) short short8;
typedef __attribute__((ext_vector_type(4))) float f32x4;

// ---------------- block reduction helpers (256 threads = 4 waves) ----------------
__device__ __forceinline__ float blk_reduce(float v, float* sb) {
  #pragma unroll
  for (int o = 32; o > 0; o >>= 1) v += __shfl_down(v, o);
  const int lane = threadIdx.x & 63, w = threadIdx.x >> 6;
  __syncthreads();
  if (lane == 0) sb[w] = v;
  __syncthreads();
  return sb[0] + sb[1] + sb[2] + sb[3];
}

__device__ __forceinline__ void blk_reduce3(float& a, float& b, float& c, float* sb) {
  #pragma unroll
  for (int o = 32; o > 0; o >>= 1) {
    a += __shfl_down(a, o); b += __shfl_down(b, o); c += __shfl_down(c, o);
  }
  const int lane = threadIdx.x & 63, w = threadIdx.x >> 6;
  __syncthreads();
  if (lane == 0) { sb[w] = a; sb[4 + w] = b; sb[8 + w] = c; }
  __syncthreads();
  a = sb[0] + sb[1] + sb[2] + sb[3];
  b = sb[4] + sb[5] + sb[6] + sb[7];
  c = sb[8] + sb[9] + sb[10] + sb[11];
}

__device__ __forceinline__ float artanh_f(float x) {
  float xc = fminf(fmaxf(x, -1.0f + 1e-5f), 1.0f - 1e-5f);
  return 0.5f * (log1pf(xc) - log1pf(-xc));
}

// bf16 round-to-nearest-even split helpers (bit math; values here are tame, no NaN/Inf)
__device__ __forceinline__ unsigned short bf16_rne(float x) {
  unsigned int u = __float_as_uint(x);
  unsigned int r = (u + 0x7fffu + ((u >> 16) & 1u)) >> 16;
  return (unsigned short)r;
}
__device__ __forceinline__ float bf16_f(unsigned short h) {
  return __uint_as_float(((unsigned int)h) << 16);
}

// Each thread owns 8 columns of a 2048-row: cols [t*4, t*4+4) and [1024+t*4, 1024+t*4+4)
__device__ __forceinline__ void load8(const float* __restrict__ rowp, int t, float* v) {
  float4 a = *(const float4*)(rowp + (t << 2));
  float4 b = *(const float4*)(rowp + 1024 + (t << 2));
  v[0] = a.x; v[1] = a.y; v[2] = a.z; v[3] = a.w;
  v[4] = b.x; v[5] = b.y; v[6] = b.z; v[7] = b.w;
}
__device__ __forceinline__ void store8(float* __restrict__ rowp, int t, const float* v) {
  float4 a = {v[0], v[1], v[2], v[3]}, b = {v[4], v[5], v[6], v[7]};
  *(float4*)(rowp + (t << 2)) = a;
  *(float4*)(rowp + 1024 + (t << 2)) = b;
}

// exp_map faithful to reference: norm -> tanh scale -> re-norm -> conditional project
__device__ __forceinline__ void exp_map8(const float* in, float* outv, float* sb) {
  float s2 = 0.f;
  #pragma unroll
  for (int j = 0; j < 8; ++j) s2 += in[j] * in[j];
  s2 = blk_reduce(s2, sb);
  float un = fmaxf(sqrtf(s2), MINNORM);
  float tt = tanhf(fminf(un, 15.0f));
  float scl = tt / un;
  float sx = 0.f;
  #pragma unroll
  for (int j = 0; j < 8; ++j) { outv[j] = scl * in[j]; sx += outv[j] * outv[j]; }
  sx = blk_reduce(sx, sb);
  float xn = fmaxf(sqrtf(sx), MINNORM);
  if (xn > MAXNORM) {            // uniform across block (xn is reduced)
    float f = MAXNORM / xn;
    #pragma unroll
    for (int j = 0; j < 8; ++j) outv[j] *= f;
  }
}

__device__ __forceinline__ void mobius8(const float* x, const float* y, float* h, float* sb) {
  float x2 = 0.f, y2 = 0.f, xy = 0.f;
  #pragma unroll
  for (int j = 0; j < 8; ++j) { x2 += x[j]*x[j]; y2 += y[j]*y[j]; xy += x[j]*y[j]; }
  blk_reduce3(x2, y2, xy, sb);
  float n1 = 1.f + 2.f*xy + y2;
  float n2 = 1.f - x2;
  float den = fmaxf(1.f + 2.f*xy + x2*y2, MINNORM);
  #pragma unroll
  for (int j = 0; j < 8; ++j) h[j] = (n1*x[j] + n2*y[j]) / den;
}

__device__ __forceinline__ void pe8(int row, int t, const float* __restrict__ divt, float* pe) {
  #pragma unroll
  for (int j = 0; j < 8; ++j) {
    int col = (j < 4) ? ((t << 2) + j) : (1024 + (t << 2) + (j - 4));
    float ang = (float)row * divt[col >> 1];
    pe[j] = (col & 1) ? cosf(ang) : sinf(ang);
  }
}

// ---------------- kernel 0: div table + rowmap init ----------------
__global__ __launch_bounds__(256) void k_init(float* __restrict__ divt, int* __restrict__ rowmap) {
  int i = blockIdx.x * 256 + threadIdx.x;
  if (i < 1024) divt[i] = expf((float)(2 * i) * (-0.004497236509753996f)); // -ln(1e4)/2048
  if (i < S_TOK) rowmap[i] = 0;
}

// rowmap: 0 normal, -1 zeroed (rest/attr), g+1 main
__global__ __launch_bounds__(256) void k_rowmap(const int* __restrict__ nflat,
                                                const int* __restrict__ aflat,
                                                int* __restrict__ rowmap) {
  int i = blockIdx.x * 256 + threadIdx.x;
  if (i < GN) {
    rowmap[nflat[i]] = ((i & 3) == 0) ? ((i >> 2) + 1) : -1;
  } else if (i < 2 * GN) {
    rowmap[aflat[i - GN]] = -1;
  }
}

// ---------------- kernel 1: hyper rows for gathered indices ----------------
__global__ __launch_bounds__(256) void k_hyper_gather(const float* __restrict__ prompt,
                                                      const int* __restrict__ nflat,
                                                      const int* __restrict__ aflat,
                                                      const float* __restrict__ divt,
                                                      float* __restrict__ Hg) {
  __shared__ float sb[12];
  const int j = blockIdx.x;
  const int t = threadIdx.x;
  const int row = (j < GN) ? nflat[j] : aflat[j - GN];
  const float* pr = prompt + (size_t)row * E_DIM;

  float p[8], x[8], pev[8], y[8], h[8];
  load8(pr, t, p);
  exp_map8(p, x, sb);
  pe8(row, t, divt, pev);
  exp_map8(pev, y, sb);
  mobius8(x, y, h, sb);
  store8(Hg + (size_t)j * E_DIM, t, h);
}

// ---------------- fp32 GEMM tile body (used by k_proj) ----------------
__device__ __forceinline__ void gemm_body(float As[16][132], float Bs[16][132],
    const float* __restrict__ ar0, const float* __restrict__ ar1,
    const float* __restrict__ br0, const float* __restrict__ br1,
    const float* __restrict__ bias, float* __restrict__ C, int ldC,
    int bm, int bn, int kbeg, int kend, int addBias)
{
  const int tid = threadIdx.x;
  const int lr = tid >> 2;          // loader row 0..63
  const int kf = (tid & 3) << 2;    // k offset 0,4,8,12
  const int tr = (tid >> 4) << 3;
  const int tc = (tid & 15) << 3;

  float acc[8][8];
  #pragma unroll
  for (int i = 0; i < 8; ++i)
    #pragma unroll
    for (int j = 0; j < 8; ++j) acc[i][j] = 0.f;

  float4 ca0 = *(const float4*)(ar0 + kbeg + kf);
  float4 ca1 = *(const float4*)(ar1 + kbeg + kf);
  float4 cb0 = *(const float4*)(br0 + kbeg + kf);
  float4 cb1 = *(const float4*)(br1 + kbeg + kf);

  for (int k0 = kbeg; k0 < kend; k0 += 16) {
    __syncthreads();
    As[kf+0][lr] = ca0.x; As[kf+1][lr] = ca0.y; As[kf+2][lr] = ca0.z; As[kf+3][lr] = ca0.w;
    As[kf+0][64+lr] = ca1.x; As[kf+1][64+lr] = ca1.y; As[kf+2][64+lr] = ca1.z; As[kf+3][64+lr] = ca1.w;
    Bs[kf+0][lr] = cb0.x; Bs[kf+1][lr] = cb0.y; Bs[kf+2][lr] = cb0.z; Bs[kf+3][lr] = cb0.w;
    Bs[kf+0][64+lr] = cb1.x; Bs[kf+1][64+lr] = cb1.y; Bs[kf+2][64+lr] = cb1.z; Bs[kf+3][64+lr] = cb1.w;
    __syncthreads();
    if (k0 + 16 < kend) {
      ca0 = *(const float4*)(ar0 + k0 + 16 + kf);
      ca1 = *(const float4*)(ar1 + k0 + 16 + kf);
      cb0 = *(const float4*)(br0 + k0 + 16 + kf);
      cb1 = *(const float4*)(br1 + k0 + 16 + kf);
    }
    #pragma unroll
    for (int k = 0; k < 16; ++k) {
      float a8[8], b8[8];
      *(float4*)&a8[0] = *(const float4*)&As[k][tr];
      *(float4*)&a8[4] = *(const float4*)&As[k][tr + 4];
      *(float4*)&b8[0] = *(const float4*)&Bs[k][tc];
      *(float4*)&b8[4] = *(const float4*)&Bs[k][tc + 4];
      #pragma unroll
      for (int i = 0; i < 8; ++i)
        #pragma unroll
        for (int j = 0; j < 8; ++j)
          acc[i][j] = fmaf(a8[i], b8[j], acc[i][j]);
    }
  }

  float4 bi0, bi1;
  if (addBias) {
    bi0 = *(const float4*)(bias + bn + tc);
    bi1 = *(const float4*)(bias + bn + tc + 4);
  } else {
    bi0 = make_float4(0.f, 0.f, 0.f, 0.f);
    bi1 = make_float4(0.f, 0.f, 0.f, 0.f);
  }
  #pragma unroll
  for (int i = 0; i < 8; ++i) {
    float* crow = C + (size_t)(bm + tr + i) * ldC + bn + tc;
    float4 o0, o1;
    o0.x = acc[i][0] + bi0.x; o0.y = acc[i][1] + bi0.y;
    o0.z = acc[i][2] + bi0.z; o0.w = acc[i][3] + bi0.w;
    o1.x = acc[i][4] + bi1.x; o1.y = acc[i][5] + bi1.y;
    o1.z = acc[i][6] + bi1.z; o1.w = acc[i][7] + bi1.w;
    *(float4*)crow = o0;
    *(float4*)(crow + 4) = o1;
  }
}

// Fused Q + KV projection (fp32). 768 blocks, XCD-chunked swizzle (768 = 8 x 96).
__global__ __launch_bounds__(256, 3) void k_proj(const float* __restrict__ prompt,
                                                 const float* __restrict__ Hg,
                                                 const int* __restrict__ nflat,
                                                 const int* __restrict__ aflat,
                                                 const float* __restrict__ w_in,
                                                 const float* __restrict__ b_in,
                                                 float* __restrict__ QO,
                                                 float* __restrict__ KV) {
  __shared__ float As[16][132];
  __shared__ float Bs[16][132];
  const int b = blockIdx.x;
  const int w = (b & 7) * 96 + (b >> 3);

  int bm, bn, hoff, ldC;
  const int* gidx;
  const float* W; const float* bias; float* C;
  if (w < 256) {
    bm = (w >> 4) << 7; bn = (w & 15) << 7;
    gidx = nflat; hoff = 0; W = w_in; bias = b_in; C = QO; ldC = E_DIM;
  } else {
    const int v = w - 256;
    bm = (v >> 5) << 7; bn = (v & 31) << 7;
    gidx = aflat; hoff = GN; W = w_in + (size_t)E_DIM * KD; bias = b_in + E_DIM; C = KV; ldC = NKV;
  }

  const int lr = threadIdx.x >> 2;
  int m0 = bm + lr, m1 = bm + 64 + lr;
  const float* ar0 = (m0 < GN) ? (prompt + (size_t)gidx[m0] * KD)
                               : (Hg + (size_t)(m0 - GN + hoff) * KD);
  const float* ar1 = (m1 < GN) ? (prompt + (size_t)gidx[m1] * KD)
                               : (Hg + (size_t)(m1 - GN + hoff) * KD);
  const float* br0 = W + (size_t)(bn + lr) * KD;
  const float* br1 = W + (size_t)(bn + 64 + lr) * KD;

  gemm_body(As, Bs, ar0, ar1, br0, br1, bias, C, ldC, bm, bn, 0, KD, 1);
}

// ---------------- split QO and w_out into bf16 hi/lo pairs ----------------
// 8192 blocks x 256 threads, 4 floats/thread.
__global__ __launch_bounds__(256) void k_split(const float* __restrict__ QO,
                                               const float* __restrict__ w_out,
                                               unsigned short* __restrict__ Qhi,
                                               unsigned short* __restrict__ Qlo,
                                               unsigned short* __restrict__ Whi,
                                               unsigned short* __restrict__ Wlo) {
  const size_t N = (size_t)E_DIM * E_DIM;
  size_t i = ((size_t)blockIdx.x * 256 + threadIdx.x) << 2;
  const float* src; unsigned short* dh; unsigned short* dl; size_t off;
  if (i < N) { src = QO; dh = Qhi; dl = Qlo; off = i; }
  else       { src = w_out; dh = Whi; dl = Wlo; off = i - N; }
  float4 v = *(const float4*)(src + off);
  ushort4 h, l;
  h.x = bf16_rne(v.x); l.x = bf16_rne(v.x - bf16_f(h.x));
  h.y = bf16_rne(v.y); l.y = bf16_rne(v.y - bf16_f(h.y));
  h.z = bf16_rne(v.z); l.z = bf16_rne(v.z - bf16_f(h.z));
  h.w = bf16_rne(v.w); l.w = bf16_rne(v.w - bf16_f(h.w));
  *(ushort4*)(dh + off) = h;
  *(ushort4*)(dl + off) = l;
}

// ---------------- out-projection via bf16 split-3 MFMA, split-K=2 ----------------
// C[m][n] = sum_k QO[m][k]*w_out[n][k] (+ b_out[n] on k-half 0)
// 128x128 tile, 4 waves (2x2), 64x64 per wave = 4x4 MFMA frags of 16x16, BK=32.
// MFMA f32_16x16x32_bf16 layouts (HW-verified, learn_hip m89):
//   A-operand: lane holds A[m=lane&15][k=(lane>>4)*8+j], j=0..7  (8 consecutive k)
//   B-operand: lane holds B'[n=lane&15][k=(lane>>4)*8+j]         (B' = W rows = n)
//   C/D:       col=lane&15, row=(lane>>4)*4+reg
// LDS rows padded to 40 ushorts (80 B) -> start bank 20*row mod 32: uniform 8-deep
// bank load for both staging writes and fragment reads (ideal for b128).
__global__ __launch_bounds__(256, 2) void k_gemm_out_mfma(
    const unsigned short* __restrict__ Ahi, const unsigned short* __restrict__ Alo,
    const unsigned short* __restrict__ Bhi, const unsigned short* __restrict__ Blo,
    const float* __restrict__ bias,
    float* __restrict__ C0, float* __restrict__ C1) {
  __shared__ short Ah_s[128][40];
  __shared__ short Al_s[128][40];
  __shared__ short Bh_s[128][40];
  __shared__ short Bl_s[128][40];

  const int b = blockIdx.x;
  const int w = (b & 7) * 64 + (b >> 3);   // 512 = 8 x 64 XCD-chunked swizzle
  const int kh = w >> 8;                   // k half: 0 or 1
  const int v = w & 255;
  const int bm = (v >> 4) << 7, bn = (v & 15) << 7;

  const int tid = threadIdx.x;
  const int lane = tid & 63;
  const int wm = (tid >> 7) & 1;           // wave row (waves 0,1 | 2,3)
  const int wn = (tid >> 6) & 1;           // wave col
  const int lrow = tid >> 1;               // staging row 0..127
  const int lh  = (tid & 1) << 4;          // staging k-offset 0 or 16 (ushorts)
  const int frow = lane & 15;              // frag row (A) / col (B,D)
  const int fkg  = lane >> 4;              // frag k-group 0..3

  const size_t arow = (size_t)(bm + lrow) * E_DIM;
  const size_t brow = (size_t)(bn + lrow) * E_DIM;
  const int kbeg = kh << 10;

  f32x4 acc[4][4];
  #pragma unroll
  for (int m = 0; m < 4; ++m)
    #pragma unroll
    for (int n = 0; n < 4; ++n)
      acc[m][n] = (f32x4){0.f, 0.f, 0.f, 0.f};

  // prefetch first k-tile (16 ushorts per array per thread = 2 x 16B)
  short8 pah0 = *(const short8*)(Ahi + arow + kbeg + lh);
  short8 pah1 = *(const short8*)(Ahi + arow + kbeg + lh + 8);
  short8 pal0 = *(const short8*)(Alo + arow + kbeg + lh);
  short8 pal1 = *(const short8*)(Alo + arow + kbeg + lh + 8);
  short8 pbh0 = *(const short8*)(Bhi + brow + kbeg + lh);
  short8 pbh1 = *(const short8*)(Bhi + brow + kbeg + lh + 8);
  short8 pbl0 = *(const short8*)(Blo + brow + kbeg + lh);
  short8 pbl1 = *(const short8*)(Blo + brow + kbeg + lh + 8);

  for (int k0 = 0; k0 < 1024; k0 += 32) {
    __syncthreads();   // previous tile's readers done
    *(short8*)&Ah_s[lrow][lh]     = pah0;
    *(short8*)&Ah_s[lrow][lh + 8] = pah1;
    *(short8*)&Al_s[lrow][lh]     = pal0;
    *(short8*)&Al_s[lrow][lh + 8] = pal1;
    *(short8*)&Bh_s[lrow][lh]     = pbh0;
    *(short8*)&Bh_s[lrow][lh + 8] = pbh1;
    *(short8*)&Bl_s[lrow][lh]     = pbl0;
    *(short8*)&Bl_s[lrow][lh + 8] = pbl1;
    __syncthreads();
    if (k0 + 32 < 1024) {   // prefetch next tile; hidden under MFMA loop
      const size_t ka = arow + kbeg + k0 + 32 + lh;
      const size_t kb = brow + kbeg + k0 + 32 + lh;
      pah0 = *(const short8*)(Ahi + ka); pah1 = *(const short8*)(Ahi + ka + 8);
      pal0 = *(const short8*)(Alo + ka); pal1 = *(const short8*)(Alo + ka + 8);
      pbh0 = *(const short8*)(Bhi + kb); pbh1 = *(const short8*)(Bhi + kb + 8);
      pbl0 = *(const short8*)(Blo + kb); pbl1 = *(const short8*)(Blo + kb + 8);
    }

    short8 ah[4], al[4];
    #pragma unroll
    for (int m = 0; m < 4; ++m) {
      ah[m] = *(const short8*)&Ah_s[wm * 64 + m * 16 + frow][fkg * 8];
      al[m] = *(const short8*)&Al_s[wm * 64 + m * 16 + frow][fkg * 8];
    }
    #pragma unroll
    for (int n = 0; n < 4; ++n) {
      short8 bh = *(const short8*)&Bh_s[wn * 64 + n * 16 + frow][fkg * 8];
      short8 bl = *(const short8*)&Bl_s[wn * 64 + n * 16 + frow][fkg * 8];
      #pragma unroll
      for (int m = 0; m < 4; ++m) {
        acc[m][n] = __builtin_amdgcn_mfma_f32_16x16x32_bf16(ah[m], bh, acc[m][n], 0, 0, 0);
        acc[m][n] = __builtin_amdgcn_mfma_f32_16x16x32_bf16(ah[m], bl, acc[m][n], 0, 0, 0);
        acc[m][n] = __builtin_amdgcn_mfma_f32_16x16x32_bf16(al[m], bh, acc[m][n], 0, 0, 0);
      }
    }
  }

  float* C = kh ? C1 : C0;
  #pragma unroll
  for (int n = 0; n < 4; ++n) {
    const int col = bn + wn * 64 + n * 16 + frow;
    const float bv = kh ? 0.f : bias[col];
    #pragma unroll
    for (int m = 0; m < 4; ++m) {
      const int r0 = bm + wm * 64 + m * 16 + fkg * 4;
      #pragma unroll
      for (int r = 0; r < 4; ++r)
        C[(size_t)(r0 + r) * E_DIM + col] = acc[m][n][r] + bv;
    }
  }
}

// ---------------- attention: per (path, group) block; overwrites Q rows with O ----------------
__global__ __launch_bounds__(256) void k_attn(float* __restrict__ QO,
                                              const float* __restrict__ KV) {
  __shared__ float sc_s[NHEAD][4][4];
  __shared__ float attn_s[NHEAD][4][4];
  const int b = blockIdx.x;
  const int p = b >> 8;          // 0 = euclid, 1 = hyper
  const int g = b & 255;
  const int t = threadIdx.x;
  const int base = p * GN + g * 4;

  if (t < 128) {
    const int h = t >> 4, qi = (t >> 2) & 3, ki = t & 3;
    const float4* q4 = (const float4*)(QO + (size_t)(base + qi) * E_DIM + h * HDIM);
    const float4* k4 = (const float4*)(KV + (size_t)(base + ki) * NKV + h * HDIM);
    float s = 0.f;
    #pragma unroll 8
    for (int d = 0; d < 64; ++d) {
      float4 a = q4[d], bb = k4[d];
      s = fmaf(a.x, bb.x, s); s = fmaf(a.y, bb.y, s);
      s = fmaf(a.z, bb.z, s); s = fmaf(a.w, bb.w, s);
    }
    sc_s[h][qi][ki] = s * (1.0f / 16.0f);   // 1/sqrt(256)
  }
  __syncthreads();
  if (t < 32) {
    const int h = t >> 2, qi = t & 3;
    float m = fmaxf(fmaxf(sc_s[h][qi][0], sc_s[h][qi][1]),
                    fmaxf(sc_s[h][qi][2], sc_s[h][qi][3]));
    float e0 = expf(sc_s[h][qi][0] - m), e1 = expf(sc_s[h][qi][1] - m);
    float e2 = expf(sc_s[h][qi][2] - m), e3 = expf(sc_s[h][qi][3] - m);
    float inv = 1.f / (e0 + e1 + e2 + e3);
    attn_s[h][qi][0] = e0 * inv; attn_s[h][qi][1] = e1 * inv;
    attn_s[h][qi][2] = e2 * inv; attn_s[h][qi][3] = e3 * inv;
  }
  __syncthreads();   // all q reads done; safe to overwrite QO rows of this block

  #pragma unroll
  for (int ch = 0; ch < 2; ++ch) {
    const int c = (ch << 10) + (t << 2);
    const int h = c >> 8;
    float4 acc[4];
    #pragma unroll
    for (int qi = 0; qi < 4; ++qi) { acc[qi].x = 0; acc[qi].y = 0; acc[qi].z = 0; acc[qi].w = 0; }
    #pragma unroll
    for (int ki = 0; ki < 4; ++ki) {
      const float4 vv = *(const float4*)(KV + (size_t)(base + ki) * NKV + E_DIM + c);
      #pragma unroll
      for (int qi = 0; qi < 4; ++qi) {
        const float a = attn_s[h][qi][ki];
        acc[qi].x = fmaf(a, vv.x, acc[qi].x); acc[qi].y = fmaf(a, vv.y, acc[qi].y);
        acc[qi].z = fmaf(a, vv.z, acc[qi].z); acc[qi].w = fmaf(a, vv.w, acc[qi].w);
      }
    }
    #pragma unroll
    for (int qi = 0; qi < 4; ++qi)
      *(float4*)(QO + (size_t)(base + qi) * E_DIM + c) = acc[qi];
  }
}

// ---------------- merge: per group -> ms_e, ms_h  (AO rows = AO + AO2, split-K halves) ----------------
__global__ __launch_bounds__(256) void k_merge(const float* __restrict__ prompt,
                                               const float* __restrict__ AO,
                                               const float* __restrict__ AO2,
                                               const float* __restrict__ Hg,
                                               const int* __restrict__ nflat,
                                               const int* __restrict__ aflat,
                                               float* __restrict__ MSe,
                                               float* __restrict__ MSh) {
  __shared__ float sb[12];
  const int g = blockIdx.x;
  const int t = threadIdx.x;

  float Se[8] = {0,0,0,0,0,0,0,0}, Sh[8] = {0,0,0,0,0,0,0,0};
  for (int j = 0; j < 4; ++j) {
    const int m = g * 4 + j;
    float a0[8], a1[8], ne[8];
    load8(AO + (size_t)m * E_DIM, t, a0);
    load8(AO2 + (size_t)m * E_DIM, t, a1);
    load8(prompt + (size_t)nflat[m] * E_DIM, t, ne);
    #pragma unroll
    for (int c = 0; c < 8; ++c) Se[c] += a0[c] + a1[c] + ne[c];

    float x0[8], x1[8], x[8], y[8], h[8];
    load8(AO + (size_t)(GN + m) * E_DIM, t, x0);   // ao_h row (half 0)
    load8(AO2 + (size_t)(GN + m) * E_DIM, t, x1);  // ao_h row (half 1)
    #pragma unroll
    for (int c = 0; c < 8; ++c) x[c] = x0[c] + x1[c];
    load8(Hg + (size_t)m * E_DIM, t, y);           // nv_h row
    mobius8(x, y, h, sb);
    #pragma unroll
    for (int c = 0; c < 8; ++c) Sh[c] += h[c];
  }

  float Ae[8] = {0,0,0,0,0,0,0,0}, Ah[8] = {0,0,0,0,0,0,0,0};
  for (int j = 0; j < 4; ++j) {
    const int m = g * 4 + j;
    float ve[8], vh[8];
    load8(prompt + (size_t)aflat[m] * E_DIM, t, ve);
    load8(Hg + (size_t)(GN + m) * E_DIM, t, vh);
    #pragma unroll
    for (int c = 0; c < 8; ++c) { Ae[c] += ve[c]; Ah[c] += vh[c]; }
  }

  float mse[8];
  #pragma unroll
  for (int c = 0; c < 8; ++c) mse[c] = ALPHA_C * Se[c] + BETA_C * Ae[c];
  store8(MSe + (size_t)g * E_DIM, t, mse);

  float xs[8], ys[8], msh[8];
  #pragma unroll
  for (int c = 0; c < 8; ++c) { xs[c] = ALPHA_C * Sh[c]; ys[c] = BETA_C * Ah[c]; }
  mobius8(xs, ys, msh, sb);
  store8(MSh + (size_t)g * E_DIM, t, msh);
}

// ---------------- final: out = eu + 0.1*log_map(hyper) with scatter semantics ----------------
__global__ __launch_bounds__(256) void k_final(const float* __restrict__ prompt,
                                               const float* __restrict__ divt,
                                               const int* __restrict__ rowmap,
                                               const float* __restrict__ MSe,
                                               const float* __restrict__ MSh,
                                               float* __restrict__ out) {
  __shared__ float sb[12];
  const int s = blockIdx.x;
  const int t = threadIdx.x;
  float* orow = out + (size_t)s * E_DIM;
  const int c = rowmap[s];

  if (c == -1) {   // rest/attr rows: eu=0, hyper=0 -> out=0
    float z[8] = {0,0,0,0,0,0,0,0};
    store8(orow, t, z);
    return;
  }

  if (c > 0) {     // main rows: out = ms_e + 0.1*log_map(ms_h)
    const int g = c - 1;
    float e[8], h[8];
    load8(MSe + (size_t)g * E_DIM, t, e);
    load8(MSh + (size_t)g * E_DIM, t, h);
    float h2 = 0.f;
    #pragma unroll
    for (int j = 0; j < 8; ++j) h2 += h[j] * h[j];
    h2 = blk_reduce(h2, sb);
    float yn = fmaxf(sqrtf(h2), MINNORM);
    float scl = 0.1f * artanh_f(yn) / yn;
    float o[8];
    #pragma unroll
    for (int j = 0; j < 8; ++j) o[j] = e[j] + scl * h[j];
    store8(orow, t, o);
    return;
  }

  // normal rows: hyper = mobius(exp_map(p), exp_map(pe)); out = p + 0.1*log_map(hyper)
  float p[8], x[8], pev[8], y[8], h[8];
  load8(prompt + (size_t)s * E_DIM, t, p);
  exp_map8(p, x, sb);
  pe8(s, t, divt, pev);
  exp_map8(pev, y, sb);
  mobius8(x, y, h, sb);
  float h2 = 0.f;
  #pragma unroll
  for (int j = 0; j < 8; ++j) h2 += h[j] * h[j];
  h2 = blk_reduce(h2, sb);
  float yn = fmaxf(sqrtf(h2), MINNORM);
  float scl = 0.1f * artanh_f(yn) / yn;
  float o[8];
  #pragma unroll
  for (int j = 0; j < 8; ++j) o[j] = p[j] + scl * h[j];
  store8(orow, t, o);
}

// ---------------- launch ----------------
extern "C" void kernel_launch(void* const* d_in, const int* in_sizes, int n_in,
                              void* d_out, int out_size, void* d_ws, size_t ws_size,
                              hipStream_t stream) {
  const float* prompt = (const float*)d_in[0];
  const float* w_in   = (const float*)d_in[1];
  const float* b_in   = (const float*)d_in[2];
  const float* w_out  = (const float*)d_in[3];
  const float* b_out  = (const float*)d_in[4];
  const int*   nidx   = (const int*)d_in[5];   // flat G*4
  const int*   aidx   = (const int*)d_in[6];   // flat G*4
  float* out = (float*)d_out;

  // workspace layout (floats unless noted); total ~101.4 MB
  //   Qhi/Qlo alias the FIRST half of KV (dead after k_attn; k_split runs after k_attn).
  //   AO2     aliases the SECOND half of KV (dead after k_attn).
  float* f    = (float*)d_ws;
  float* Hg   = f;                                // [2048][2048]
  float* QO   = Hg  + (size_t)MROWS * E_DIM;      // [2048][2048]
  float* KV   = QO  + (size_t)MROWS * E_DIM;      // [2048][4096]
  unsigned short* Qhi = (unsigned short*)KV;                   // [2048][2048] ushort
  unsigned short* Qlo = Qhi + (size_t)E_DIM * E_DIM;           // [2048][2048] ushort
  float* AO2  = KV  + (size_t)MROWS * E_DIM;      // [2048][2048] (out-proj k half 1)
  float* AO   = KV  + (size_t)MROWS * NKV;        // [2048][2048] (out-proj k half 0, +bias)
  float* MSe  = AO  + (size_t)MROWS * E_DIM;      // [256][2048]
  float* MSh  = MSe + (size_t)NGRP * E_DIM;       // [256][2048]
  float* divt = MSh + (size_t)NGRP * E_DIM;       // [1024]
  int* rowmap = (int*)(divt + 1024);              // [8192]
  unsigned short* Whi = (unsigned short*)(rowmap + S_TOK);     // [2048][2048] ushort
  unsigned short* Wlo = Whi + (size_t)E_DIM * E_DIM;           // [2048][2048] ushort

  k_init<<<32, 256, 0, stream>>>(divt, rowmap);
  k_rowmap<<<8, 256, 0, stream>>>(nidx, aidx, rowmap);
  k_hyper_gather<<<MROWS, 256, 0, stream>>>(prompt, nidx, aidx, divt, Hg);

  k_proj<<<768, 256, 0, stream>>>(prompt, Hg, nidx, aidx, w_in, b_in, QO, KV);
  k_attn<<<512, 256, 0, stream>>>(QO, KV);
  k_split<<<8192, 256, 0, stream>>>(QO, w_out, Qhi, Qlo, Whi, Wlo);
  k_gemm_out_mfma<<<512, 256, 0, stream>>>(Qhi, Qlo, Whi, Wlo, b_out, AO, AO2);
  k_merge<<<NGRP, 256, 0, stream>>>(prompt, AO, AO2, Hg, nidx, aidx, MSe, MSh);
  k_final<<<S_TOK, 256, 0, stream>>>(prompt, divt, rowmap, MSe, MSh, out);
}

// Round 5
// 463.408 us; speedup vs baseline: 2.3564x; 2.3564x over previous
//
#include <hip/hip_runtime.h>
#include <math.h>

// Problem constants (from reference)
#define S_TOK 8192
#define E_DIM 2048
#define NHEAD 8
#define HDIM  256
#define NGRP  256
#define GN    1024   // NGRP*4  (flattened noun rows; attrs same count)
#define MROWS 2048   // 2*GN    (e-path rows ++ h-path rows)
#define NKV   4096   // K and V projections side by side
#define KD    2048

#define MAXNORM 0.99999f
#define MINNORM 1e-15f
#define ALPHA_C 1.1f
#define BETA_C  1.2f

typedef __attribute__((ext_vector_type(8))) short short8;
typedef __attribute__((ext_vector_type(4))) float f32x4;

// ---------------- block reduction helpers (256 threads = 4 waves) ----------------
__device__ __forceinline__ float blk_reduce(float v, float* sb) {
  #pragma unroll
  for (int o = 32; o > 0; o >>= 1) v += __shfl_down(v, o);
  const int lane = threadIdx.x & 63, w = threadIdx.x >> 6;
  __syncthreads();
  if (lane == 0) sb[w] = v;
  __syncthreads();
  return sb[0] + sb[1] + sb[2] + sb[3];
}

__device__ __forceinline__ void blk_reduce3(float& a, float& b, float& c, float* sb) {
  #pragma unroll
  for (int o = 32; o > 0; o >>= 1) {
    a += __shfl_down(a, o); b += __shfl_down(b, o); c += __shfl_down(c, o);
  }
  const int lane = threadIdx.x & 63, w = threadIdx.x >> 6;
  __syncthreads();
  if (lane == 0) { sb[w] = a; sb[4 + w] = b; sb[8 + w] = c; }
  __syncthreads();
  a = sb[0] + sb[1] + sb[2] + sb[3];
  b = sb[4] + sb[5] + sb[6] + sb[7];
  c = sb[8] + sb[9] + sb[10] + sb[11];
}

__device__ __forceinline__ float artanh_f(float x) {
  float xc = fminf(fmaxf(x, -1.0f + 1e-5f), 1.0f - 1e-5f);
  return 0.5f * (log1pf(xc) - log1pf(-xc));
}

// bf16 round-to-nearest-even split helpers (bit math; values here are tame, no NaN/Inf)
__device__ __forceinline__ unsigned short bf16_rne(float x) {
  unsigned int u = __float_as_uint(x);
  unsigned int r = (u + 0x7fffu + ((u >> 16) & 1u)) >> 16;
  return (unsigned short)r;
}
__device__ __forceinline__ float bf16_f(unsigned short h) {
  return __uint_as_float(((unsigned int)h) << 16);
}

// Each thread owns 8 columns of a 2048-row: cols [t*4, t*4+4) and [1024+t*4, 1024+t*4+4)
__device__ __forceinline__ void load8(const float* __restrict__ rowp, int t, float* v) {
  float4 a = *(const float4*)(rowp + (t << 2));
  float4 b = *(const float4*)(rowp + 1024 + (t << 2));
  v[0] = a.x; v[1] = a.y; v[2] = a.z; v[3] = a.w;
  v[4] = b.x; v[5] = b.y; v[6] = b.z; v[7] = b.w;
}
__device__ __forceinline__ void store8(float* __restrict__ rowp, int t, const float* v) {
  float4 a = {v[0], v[1], v[2], v[3]}, b = {v[4], v[5], v[6], v[7]};
  *(float4*)(rowp + (t << 2)) = a;
  *(float4*)(rowp + 1024 + (t << 2)) = b;
}

// exp_map faithful to reference: norm -> tanh scale -> re-norm -> conditional project
__device__ __forceinline__ void exp_map8(const float* in, float* outv, float* sb) {
  float s2 = 0.f;
  #pragma unroll
  for (int j = 0; j < 8; ++j) s2 += in[j] * in[j];
  s2 = blk_reduce(s2, sb);
  float un = fmaxf(sqrtf(s2), MINNORM);
  float tt = tanhf(fminf(un, 15.0f));
  float scl = tt / un;
  float sx = 0.f;
  #pragma unroll
  for (int j = 0; j < 8; ++j) { outv[j] = scl * in[j]; sx += outv[j] * outv[j]; }
  sx = blk_reduce(sx, sb);
  float xn = fmaxf(sqrtf(sx), MINNORM);
  if (xn > MAXNORM) {            // uniform across block (xn is reduced)
    float f = MAXNORM / xn;
    #pragma unroll
    for (int j = 0; j < 8; ++j) outv[j] *= f;
  }
}

__device__ __forceinline__ void mobius8(const float* x, const float* y, float* h, float* sb) {
  float x2 = 0.f, y2 = 0.f, xy = 0.f;
  #pragma unroll
  for (int j = 0; j < 8; ++j) { x2 += x[j]*x[j]; y2 += y[j]*y[j]; xy += x[j]*y[j]; }
  blk_reduce3(x2, y2, xy, sb);
  float n1 = 1.f + 2.f*xy + y2;
  float n2 = 1.f - x2;
  float den = fmaxf(1.f + 2.f*xy + x2*y2, MINNORM);
  #pragma unroll
  for (int j = 0; j < 8; ++j) h[j] = (n1*x[j] + n2*y[j]) / den;
}

__device__ __forceinline__ void pe8(int row, int t, const float* __restrict__ divt, float* pe) {
  #pragma unroll
  for (int j = 0; j < 8; ++j) {
    int col = (j < 4) ? ((t << 2) + j) : (1024 + (t << 2) + (j - 4));
    float ang = (float)row * divt[col >> 1];
    pe[j] = (col & 1) ? cosf(ang) : sinf(ang);
  }
}

// ---------------- kernel 0: div table + rowmap init ----------------
__global__ __launch_bounds__(256) void k_init(float* __restrict__ divt, int* __restrict__ rowmap) {
  int i = blockIdx.x * 256 + threadIdx.x;
  if (i < 1024) divt[i] = expf((float)(2 * i) * (-0.004497236509753996f)); // -ln(1e4)/2048
  if (i < S_TOK) rowmap[i] = 0;
}

// rowmap: 0 normal, -1 zeroed (rest/attr), g+1 main
__global__ __launch_bounds__(256) void k_rowmap(const int* __restrict__ nflat,
                                                const int* __restrict__ aflat,
                                                int* __restrict__ rowmap) {
  int i = blockIdx.x * 256 + threadIdx.x;
  if (i < GN) {
    rowmap[nflat[i]] = ((i & 3) == 0) ? ((i >> 2) + 1) : -1;
  } else if (i < 2 * GN) {
    rowmap[aflat[i - GN]] = -1;
  }
}

// ---------------- kernel 1: hyper rows for gathered indices ----------------
__global__ __launch_bounds__(256) void k_hyper_gather(const float* __restrict__ prompt,
                                                      const int* __restrict__ nflat,
                                                      const int* __restrict__ aflat,
                                                      const float* __restrict__ divt,
                                                      float* __restrict__ Hg) {
  __shared__ float sb[12];
  const int j = blockIdx.x;
  const int t = threadIdx.x;
  const int row = (j < GN) ? nflat[j] : aflat[j - GN];
  const float* pr = prompt + (size_t)row * E_DIM;

  float p[8], x[8], pev[8], y[8], h[8];
  load8(pr, t, p);
  exp_map8(p, x, sb);
  pe8(row, t, divt, pev);
  exp_map8(pev, y, sb);
  mobius8(x, y, h, sb);
  store8(Hg + (size_t)j * E_DIM, t, h);
}

// ---------------- split w_in into bf16 hi/lo (early; weights only) ----------------
// 12288 blocks: row = b>>1 (0..6143), cols (b&1)*1024 + t*4
__global__ __launch_bounds__(256) void k_splitW(const float* __restrict__ w_in,
                                                unsigned short* __restrict__ WIhi,
                                                unsigned short* __restrict__ WIlo) {
  const int b = blockIdx.x;
  const size_t off = (size_t)(b >> 1) * E_DIM + ((b & 1) << 10) + (threadIdx.x << 2);
  float4 v = *(const float4*)(w_in + off);
  ushort4 h, l;
  h.x = bf16_rne(v.x); l.x = bf16_rne(v.x - bf16_f(h.x));
  h.y = bf16_rne(v.y); l.y = bf16_rne(v.y - bf16_f(h.y));
  h.z = bf16_rne(v.z); l.z = bf16_rne(v.z - bf16_f(h.z));
  h.w = bf16_rne(v.w); l.w = bf16_rne(v.w - bf16_f(h.w));
  *(ushort4*)(WIhi + off) = h;
  *(ushort4*)(WIlo + off) = l;
}

// ---------------- gather + split A rows into bf16 hi/lo ----------------
// Packed A [4096][2048]: rows 0..1023 prompt[nidx], 1024..2047 Hg[j-1024] (noun-h),
//                        2048..3071 prompt[aidx], 3072..4095 Hg[j-2048]  (attr-h).
// 8192 blocks: row = b>>1, cols (b&1)*1024 + t*4
__global__ __launch_bounds__(256) void k_splitA(const float* __restrict__ prompt,
                                                const float* __restrict__ Hg,
                                                const int* __restrict__ nflat,
                                                const int* __restrict__ aflat,
                                                unsigned short* __restrict__ Ahi,
                                                unsigned short* __restrict__ Alo) {
  const int b = blockIdx.x;
  const int j = b >> 1;
  const int c0 = ((b & 1) << 10) + (threadIdx.x << 2);
  const float* src;
  if (j < GN)            src = prompt + (size_t)nflat[j] * E_DIM;
  else if (j < 2 * GN)   src = Hg + (size_t)(j - GN) * E_DIM;
  else if (j < 3 * GN)   src = prompt + (size_t)aflat[j - 2 * GN] * E_DIM;
  else                   src = Hg + (size_t)(j - 2 * GN) * E_DIM;
  float4 v = *(const float4*)(src + c0);
  ushort4 h, l;
  h.x = bf16_rne(v.x); l.x = bf16_rne(v.x - bf16_f(h.x));
  h.y = bf16_rne(v.y); l.y = bf16_rne(v.y - bf16_f(h.y));
  h.z = bf16_rne(v.z); l.z = bf16_rne(v.z - bf16_f(h.z));
  h.w = bf16_rne(v.w); l.w = bf16_rne(v.w - bf16_f(h.w));
  const size_t off = (size_t)j * E_DIM + c0;
  *(ushort4*)(Ahi + off) = h;
  *(ushort4*)(Alo + off) = l;
}

// ---------------- split QO and w_out into bf16 hi/lo pairs (post-attn) ----------------
__global__ __launch_bounds__(256) void k_split(const float* __restrict__ QO,
                                               const float* __restrict__ w_out,
                                               unsigned short* __restrict__ Qhi,
                                               unsigned short* __restrict__ Qlo,
                                               unsigned short* __restrict__ Whi,
                                               unsigned short* __restrict__ Wlo) {
  const size_t N = (size_t)E_DIM * E_DIM;
  size_t i = ((size_t)blockIdx.x * 256 + threadIdx.x) << 2;
  const float* src; unsigned short* dh; unsigned short* dl; size_t off;
  if (i < N) { src = QO; dh = Qhi; dl = Qlo; off = i; }
  else       { src = w_out; dh = Whi; dl = Wlo; off = i - N; }
  float4 v = *(const float4*)(src + off);
  ushort4 h, l;
  h.x = bf16_rne(v.x); l.x = bf16_rne(v.x - bf16_f(h.x));
  h.y = bf16_rne(v.y); l.y = bf16_rne(v.y - bf16_f(h.y));
  h.z = bf16_rne(v.z); l.z = bf16_rne(v.z - bf16_f(h.z));
  h.w = bf16_rne(v.w); l.w = bf16_rne(v.w - bf16_f(h.w));
  *(ushort4*)(dh + off) = h;
  *(ushort4*)(dl + off) = l;
}

// ---------------- shared bf16 split-3 MFMA tile body ----------------
// C[bm+i][bn+j] (+= bias) = sum_k A[i][k]*B[j][k] over [kbeg,kend), A/B pre-offset
// to the block's first row. 128x128 tile, 4 waves (2x2), 64x64/wave = 4x4 frags of
// 16x16x32, BK=32. MFMA layouts HW-verified (learn_hip m89); validated end-to-end
// by round-4's passing k_gemm_out_mfma.
// LDS rows padded to 40 shorts (80 B): start bank 20*row mod 32 spreads accesses.
__device__ __forceinline__ void mfma_gemm_tile(
    short Ah_s[128][40], short Al_s[128][40], short Bh_s[128][40], short Bl_s[128][40],
    const unsigned short* __restrict__ Ahi, const unsigned short* __restrict__ Alo,
    const unsigned short* __restrict__ Bhi, const unsigned short* __restrict__ Blo,
    const float* __restrict__ bias, float* __restrict__ C, int ldC,
    int bm, int bn, int kbeg, int kend, int addBias)
{
  const int tid = threadIdx.x;
  const int lane = tid & 63;
  const int wm = (tid >> 7) & 1;           // wave row
  const int wn = (tid >> 6) & 1;           // wave col
  const int lrow = tid >> 1;               // staging row 0..127
  const int lh  = (tid & 1) << 4;          // staging k-offset 0 or 16 (shorts)
  const int frow = lane & 15;              // frag row (A) / col (B,D)
  const int fkg  = lane >> 4;              // frag k-group 0..3

  const size_t arow = (size_t)lrow * KD;
  const size_t brow = (size_t)lrow * KD;

  f32x4 acc[4][4];
  #pragma unroll
  for (int m = 0; m < 4; ++m)
    #pragma unroll
    for (int n = 0; n < 4; ++n)
      acc[m][n] = (f32x4){0.f, 0.f, 0.f, 0.f};

  short8 pah0 = *(const short8*)(Ahi + arow + kbeg + lh);
  short8 pah1 = *(const short8*)(Ahi + arow + kbeg + lh + 8);
  short8 pal0 = *(const short8*)(Alo + arow + kbeg + lh);
  short8 pal1 = *(const short8*)(Alo + arow + kbeg + lh + 8);
  short8 pbh0 = *(const short8*)(Bhi + brow + kbeg + lh);
  short8 pbh1 = *(const short8*)(Bhi + brow + kbeg + lh + 8);
  short8 pbl0 = *(const short8*)(Blo + brow + kbeg + lh);
  short8 pbl1 = *(const short8*)(Blo + brow + kbeg + lh + 8);

  for (int k0 = kbeg; k0 < kend; k0 += 32) {
    __syncthreads();   // previous tile's readers done
    *(short8*)&Ah_s[lrow][lh]     = pah0;
    *(short8*)&Ah_s[lrow][lh + 8] = pah1;
    *(short8*)&Al_s[lrow][lh]     = pal0;
    *(short8*)&Al_s[lrow][lh + 8] = pal1;
    *(short8*)&Bh_s[lrow][lh]     = pbh0;
    *(short8*)&Bh_s[lrow][lh + 8] = pbh1;
    *(short8*)&Bl_s[lrow][lh]     = pbl0;
    *(short8*)&Bl_s[lrow][lh + 8] = pbl1;
    __syncthreads();
    if (k0 + 32 < kend) {   // prefetch next tile; hidden under MFMA loop
      const size_t ka = arow + k0 + 32 + lh;
      const size_t kb = brow + k0 + 32 + lh;
      pah0 = *(const short8*)(Ahi + ka); pah1 = *(const short8*)(Ahi + ka + 8);
      pal0 = *(const short8*)(Alo + ka); pal1 = *(const short8*)(Alo + ka + 8);
      pbh0 = *(const short8*)(Bhi + kb); pbh1 = *(const short8*)(Bhi + kb + 8);
      pbl0 = *(const short8*)(Blo + kb); pbl1 = *(const short8*)(Blo + kb + 8);
    }

    short8 ah[4], al[4];
    #pragma unroll
    for (int m = 0; m < 4; ++m) {
      ah[m] = *(const short8*)&Ah_s[wm * 64 + m * 16 + frow][fkg * 8];
      al[m] = *(const short8*)&Al_s[wm * 64 + m * 16 + frow][fkg * 8];
    }
    #pragma unroll
    for (int n = 0; n < 4; ++n) {
      short8 bh = *(const short8*)&Bh_s[wn * 64 + n * 16 + frow][fkg * 8];
      short8 bl = *(const short8*)&Bl_s[wn * 64 + n * 16 + frow][fkg * 8];
      #pragma unroll
      for (int m = 0; m < 4; ++m) {
        acc[m][n] = __builtin_amdgcn_mfma_f32_16x16x32_bf16(ah[m], bh, acc[m][n], 0, 0, 0);
        acc[m][n] = __builtin_amdgcn_mfma_f32_16x16x32_bf16(ah[m], bl, acc[m][n], 0, 0, 0);
        acc[m][n] = __builtin_amdgcn_mfma_f32_16x16x32_bf16(al[m], bh, acc[m][n], 0, 0, 0);
      }
    }
  }

  #pragma unroll
  for (int n = 0; n < 4; ++n) {
    const int col = bn + wn * 64 + n * 16 + frow;
    const float bv = addBias ? bias[col] : 0.f;
    #pragma unroll
    for (int m = 0; m < 4; ++m) {
      const int r0 = bm + wm * 64 + m * 16 + fkg * 4;
      #pragma unroll
      for (int r = 0; r < 4; ++r)
        C[(size_t)(r0 + r) * ldC + col] = acc[m][n][r] + bv;
    }
  }
}

// ---------------- fused Q + KV projection via split-3 MFMA ----------------
// 768 blocks, XCD-chunked swizzle (768 = 8 x 96).
//   w <  256 : Q  gemm (16x16 tiles) -> QO [2048][2048]; A rows 0..2047, W rows 0..2047
//   w >= 256 : KV gemm (16x32 tiles) -> KV [2048][4096]; A rows 2048.., W rows 2048..
__global__ __launch_bounds__(256, 2) void k_proj_mfma(
    const unsigned short* __restrict__ Ahi, const unsigned short* __restrict__ Alo,
    const unsigned short* __restrict__ WIhi, const unsigned short* __restrict__ WIlo,
    const float* __restrict__ b_in,
    float* __restrict__ QO, float* __restrict__ KV) {
  __shared__ short Ah_s[128][40];
  __shared__ short Al_s[128][40];
  __shared__ short Bh_s[128][40];
  __shared__ short Bl_s[128][40];

  const int b = blockIdx.x;
  const int w = (b & 7) * 96 + (b >> 3);

  int bm, bn, bmA, bnB, ldC;
  const float* bias; float* C;
  if (w < 256) {
    bm = (w >> 4) << 7; bn = (w & 15) << 7;
    bmA = bm; bnB = bn; bias = b_in; C = QO; ldC = E_DIM;
  } else {
    const int v = w - 256;
    bm = (v >> 5) << 7; bn = (v & 31) << 7;
    bmA = 2048 + bm; bnB = 2048 + bn; bias = b_in + 2048; C = KV; ldC = NKV;
  }

  mfma_gemm_tile(Ah_s, Al_s, Bh_s, Bl_s,
                 Ahi + (size_t)bmA * KD, Alo + (size_t)bmA * KD,
                 WIhi + (size_t)bnB * KD, WIlo + (size_t)bnB * KD,
                 bias, C, ldC, bm, bn, 0, KD, 1);
}

// ---------------- out-projection via split-3 MFMA, split-K=2 ----------------
__global__ __launch_bounds__(256, 2) void k_gemm_out_mfma(
    const unsigned short* __restrict__ Ahi, const unsigned short* __restrict__ Alo,
    const unsigned short* __restrict__ Bhi, const unsigned short* __restrict__ Blo,
    const float* __restrict__ bias,
    float* __restrict__ C0, float* __restrict__ C1) {
  __shared__ short Ah_s[128][40];
  __shared__ short Al_s[128][40];
  __shared__ short Bh_s[128][40];
  __shared__ short Bl_s[128][40];

  const int b = blockIdx.x;
  const int w = (b & 7) * 64 + (b >> 3);   // 512 = 8 x 64 XCD-chunked swizzle
  const int kh = w >> 8;                   // k half: 0 or 1
  const int v = w & 255;
  const int bm = (v >> 4) << 7, bn = (v & 15) << 7;

  mfma_gemm_tile(Ah_s, Al_s, Bh_s, Bl_s,
                 Ahi + (size_t)bm * KD, Alo + (size_t)bm * KD,
                 Bhi + (size_t)bn * KD, Blo + (size_t)bn * KD,
                 bias, kh ? C1 : C0, E_DIM, bm, bn,
                 kh << 10, (kh << 10) + 1024, kh == 0);
}

// ---------------- attention: per (path, group) block; overwrites Q rows with O ----------------
__global__ __launch_bounds__(256) void k_attn(float* __restrict__ QO,
                                              const float* __restrict__ KV) {
  __shared__ float sc_s[NHEAD][4][4];
  __shared__ float attn_s[NHEAD][4][4];
  const int b = blockIdx.x;
  const int p = b >> 8;          // 0 = euclid, 1 = hyper
  const int g = b & 255;
  const int t = threadIdx.x;
  const int base = p * GN + g * 4;

  if (t < 128) {
    const int h = t >> 4, qi = (t >> 2) & 3, ki = t & 3;
    const float4* q4 = (const float4*)(QO + (size_t)(base + qi) * E_DIM + h * HDIM);
    const float4* k4 = (const float4*)(KV + (size_t)(base + ki) * NKV + h * HDIM);
    float s = 0.f;
    #pragma unroll 8
    for (int d = 0; d < 64; ++d) {
      float4 a = q4[d], bb = k4[d];
      s = fmaf(a.x, bb.x, s); s = fmaf(a.y, bb.y, s);
      s = fmaf(a.z, bb.z, s); s = fmaf(a.w, bb.w, s);
    }
    sc_s[h][qi][ki] = s * (1.0f / 16.0f);   // 1/sqrt(256)
  }
  __syncthreads();
  if (t < 32) {
    const int h = t >> 2, qi = t & 3;
    float m = fmaxf(fmaxf(sc_s[h][qi][0], sc_s[h][qi][1]),
                    fmaxf(sc_s[h][qi][2], sc_s[h][qi][3]));
    float e0 = expf(sc_s[h][qi][0] - m), e1 = expf(sc_s[h][qi][1] - m);
    float e2 = expf(sc_s[h][qi][2] - m), e3 = expf(sc_s[h][qi][3] - m);
    float inv = 1.f / (e0 + e1 + e2 + e3);
    attn_s[h][qi][0] = e0 * inv; attn_s[h][qi][1] = e1 * inv;
    attn_s[h][qi][2] = e2 * inv; attn_s[h][qi][3] = e3 * inv;
  }
  __syncthreads();   // all q reads done; safe to overwrite QO rows of this block

  #pragma unroll
  for (int ch = 0; ch < 2; ++ch) {
    const int c = (ch << 10) + (t << 2);
    const int h = c >> 8;
    float4 acc[4];
    #pragma unroll
    for (int qi = 0; qi < 4; ++qi) { acc[qi].x = 0; acc[qi].y = 0; acc[qi].z = 0; acc[qi].w = 0; }
    #pragma unroll
    for (int ki = 0; ki < 4; ++ki) {
      const float4 vv = *(const float4*)(KV + (size_t)(base + ki) * NKV + E_DIM + c);
      #pragma unroll
      for (int qi = 0; qi < 4; ++qi) {
        const float a = attn_s[h][qi][ki];
        acc[qi].x = fmaf(a, vv.x, acc[qi].x); acc[qi].y = fmaf(a, vv.y, acc[qi].y);
        acc[qi].z = fmaf(a, vv.z, acc[qi].z); acc[qi].w = fmaf(a, vv.w, acc[qi].w);
      }
    }
    #pragma unroll
    for (int qi = 0; qi < 4; ++qi)
      *(float4*)(QO + (size_t)(base + qi) * E_DIM + c) = acc[qi];
  }
}

// ---------------- merge: per group -> ms_e, ms_h  (AO rows = AO + AO2, split-K halves) ----------------
__global__ __launch_bounds__(256) void k_merge(const float* __restrict__ prompt,
                                               const float* __restrict__ AO,
                                               const float* __restrict__ AO2,
                                               const float* __restrict__ Hg,
                                               const int* __restrict__ nflat,
                                               const int* __restrict__ aflat,
                                               float* __restrict__ MSe,
                                               float* __restrict__ MSh) {
  __shared__ float sb[12];
  const int g = blockIdx.x;
  const int t = threadIdx.x;

  float Se[8] = {0,0,0,0,0,0,0,0}, Sh[8] = {0,0,0,0,0,0,0,0};
  for (int j = 0; j < 4; ++j) {
    const int m = g * 4 + j;
    float a0[8], a1[8], ne[8];
    load8(AO + (size_t)m * E_DIM, t, a0);
    load8(AO2 + (size_t)m * E_DIM, t, a1);
    load8(prompt + (size_t)nflat[m] * E_DIM, t, ne);
    #pragma unroll
    for (int c = 0; c < 8; ++c) Se[c] += a0[c] + a1[c] + ne[c];

    float x0[8], x1[8], x[8], y[8], h[8];
    load8(AO + (size_t)(GN + m) * E_DIM, t, x0);   // ao_h row (half 0)
    load8(AO2 + (size_t)(GN + m) * E_DIM, t, x1);  // ao_h row (half 1)
    #pragma unroll
    for (int c = 0; c < 8; ++c) x[c] = x0[c] + x1[c];
    load8(Hg + (size_t)m * E_DIM, t, y);           // nv_h row
    mobius8(x, y, h, sb);
    #pragma unroll
    for (int c = 0; c < 8; ++c) Sh[c] += h[c];
  }

  float Ae[8] = {0,0,0,0,0,0,0,0}, Ah[8] = {0,0,0,0,0,0,0,0};
  for (int j = 0; j < 4; ++j) {
    const int m = g * 4 + j;
    float ve[8], vh[8];
    load8(prompt + (size_t)aflat[m] * E_DIM, t, ve);
    load8(Hg + (size_t)(GN + m) * E_DIM, t, vh);
    #pragma unroll
    for (int c = 0; c < 8; ++c) { Ae[c] += ve[c]; Ah[c] += vh[c]; }
  }

  float mse[8];
  #pragma unroll
  for (int c = 0; c < 8; ++c) mse[c] = ALPHA_C * Se[c] + BETA_C * Ae[c];
  store8(MSe + (size_t)g * E_DIM, t, mse);

  float xs[8], ys[8], msh[8];
  #pragma unroll
  for (int c = 0; c < 8; ++c) { xs[c] = ALPHA_C * Sh[c]; ys[c] = BETA_C * Ah[c]; }
  mobius8(xs, ys, msh, sb);
  store8(MSh + (size_t)g * E_DIM, t, msh);
}

// ---------------- final: out = eu + 0.1*log_map(hyper) with scatter semantics ----------------
__global__ __launch_bounds__(256) void k_final(const float* __restrict__ prompt,
                                               const float* __restrict__ divt,
                                               const int* __restrict__ rowmap,
                                               const float* __restrict__ MSe,
                                               const float* __restrict__ MSh,
                                               float* __restrict__ out) {
  __shared__ float sb[12];
  const int s = blockIdx.x;
  const int t = threadIdx.x;
  float* orow = out + (size_t)s * E_DIM;
  const int c = rowmap[s];

  if (c == -1) {   // rest/attr rows: eu=0, hyper=0 -> out=0
    float z[8] = {0,0,0,0,0,0,0,0};
    store8(orow, t, z);
    return;
  }

  if (c > 0) {     // main rows: out = ms_e + 0.1*log_map(ms_h)
    const int g = c - 1;
    float e[8], h[8];
    load8(MSe + (size_t)g * E_DIM, t, e);
    load8(MSh + (size_t)g * E_DIM, t, h);
    float h2 = 0.f;
    #pragma unroll
    for (int j = 0; j < 8; ++j) h2 += h[j] * h[j];
    h2 = blk_reduce(h2, sb);
    float yn = fmaxf(sqrtf(h2), MINNORM);
    float scl = 0.1f * artanh_f(yn) / yn;
    float o[8];
    #pragma unroll
    for (int j = 0; j < 8; ++j) o[j] = e[j] + scl * h[j];
    store8(orow, t, o);
    return;
  }

  // normal rows: hyper = mobius(exp_map(p), exp_map(pe)); out = p + 0.1*log_map(hyper)
  float p[8], x[8], pev[8], y[8], h[8];
  load8(prompt + (size_t)s * E_DIM, t, p);
  exp_map8(p, x, sb);
  pe8(s, t, divt, pev);
  exp_map8(pev, y, sb);
  mobius8(x, y, h, sb);
  float h2 = 0.f;
  #pragma unroll
  for (int j = 0; j < 8; ++j) h2 += h[j] * h[j];
  h2 = blk_reduce(h2, sb);
  float yn = fmaxf(sqrtf(h2), MINNORM);
  float scl = 0.1f * artanh_f(yn) / yn;
  float o[8];
  #pragma unroll
  for (int j = 0; j < 8; ++j) o[j] = p[j] + scl * h[j];
  store8(orow, t, o);
}

// ---------------- launch ----------------
extern "C" void kernel_launch(void* const* d_in, const int* in_sizes, int n_in,
                              void* d_out, int out_size, void* d_ws, size_t ws_size,
                              hipStream_t stream) {
  const float* prompt = (const float*)d_in[0];
  const float* w_in   = (const float*)d_in[1];
  const float* b_in   = (const float*)d_in[2];
  const float* w_out  = (const float*)d_in[3];
  const float* b_out  = (const float*)d_in[4];
  const int*   nidx   = (const int*)d_in[5];   // flat G*4
  const int*   aidx   = (const int*)d_in[6];   // flat G*4
  float* out = (float*)d_out;

  // workspace layout; total ~151 MB. Aliasing (stream-ordered, safe):
  //   Qhi/Qlo/WOhi/WOlo live in the A-split region (A dead after k_proj_mfma).
  //   AO/AO2 live in the WI-split region (WI dead after k_proj_mfma).
  char* base = (char*)d_ws;
  float* Hg   = (float*)base;                                   //  16.78 MB [2048][2048]
  float* QO   = Hg + (size_t)MROWS * E_DIM;                     //  16.78 MB [2048][2048]
  float* KV   = QO + (size_t)MROWS * E_DIM;                     //  33.55 MB [2048][4096]
  unsigned short* Ahi = (unsigned short*)(KV + (size_t)MROWS * NKV);  // 16.78 MB [4096][2048]
  unsigned short* Alo = Ahi + (size_t)4096 * E_DIM;                   // 16.78 MB
  unsigned short* WIhi = Alo + (size_t)4096 * E_DIM;                  // 25.17 MB [6144][2048]
  unsigned short* WIlo = WIhi + (size_t)6144 * E_DIM;                 // 25.17 MB
  float* MSe  = (float*)(WIlo + (size_t)6144 * E_DIM);          //   2.10 MB [256][2048]
  float* MSh  = MSe + (size_t)NGRP * E_DIM;                     //   2.10 MB
  float* divt = MSh + (size_t)NGRP * E_DIM;                     //   4 KB
  int* rowmap = (int*)(divt + 1024);                            //  32 KB
  // aliases:
  unsigned short* Qhi  = Ahi;                                   // [2048][2048] (A region)
  unsigned short* Qlo  = Qhi + (size_t)E_DIM * E_DIM;
  unsigned short* WOhi = Qlo + (size_t)E_DIM * E_DIM;
  unsigned short* WOlo = WOhi + (size_t)E_DIM * E_DIM;
  float* AO  = (float*)WIhi;                                    // [2048][2048] (WI region)
  float* AO2 = AO + (size_t)MROWS * E_DIM;                      // [2048][2048]

  k_init<<<32, 256, 0, stream>>>(divt, rowmap);
  k_rowmap<<<8, 256, 0, stream>>>(nidx, aidx, rowmap);
  k_splitW<<<12288, 256, 0, stream>>>(w_in, WIhi, WIlo);
  k_hyper_gather<<<MROWS, 256, 0, stream>>>(prompt, nidx, aidx, divt, Hg);
  k_splitA<<<8192, 256, 0, stream>>>(prompt, Hg, nidx, aidx, Ahi, Alo);

  k_proj_mfma<<<768, 256, 0, stream>>>(Ahi, Alo, WIhi, WIlo, b_in, QO, KV);
  k_attn<<<512, 256, 0, stream>>>(QO, KV);
  k_split<<<8192, 256, 0, stream>>>(QO, w_out, Qhi, Qlo, WOhi, WOlo);
  k_gemm_out_mfma<<<512, 256, 0, stream>>>(Qhi, Qlo, WOhi, WOlo, b_out, AO, AO2);
  k_merge<<<NGRP, 256, 0, stream>>>(prompt, AO, AO2, Hg, nidx, aidx, MSe, MSh);
  k_final<<<S_TOK, 256, 0, stream>>>(prompt, divt, rowmap, MSe, MSh, out);
}